// Round 4
// baseline (648.104 us; speedup 1.0000x reference)
//
#include <hip/hip_runtime.h>
#include <math.h>

#define DT 0.1f
#define BM 64
#define BN 64

typedef __attribute__((ext_vector_type(8))) short short8;
typedef __attribute__((ext_vector_type(4))) short short4v;
typedef __attribute__((ext_vector_type(4))) float f32x4;

__device__ __forceinline__ short f2bf(float x) {
    unsigned int u = __float_as_uint(x);
    unsigned int r = (u + 0x7fffu + ((u >> 16) & 1u)) >> 16;  // RNE
    return (short)r;
}
__device__ __forceinline__ float bf2f(short s) {
    return __uint_as_float(((unsigned int)(unsigned short)s) << 16);
}
__device__ __forceinline__ float tanh_fast(float x) {
    float e = __expf(2.f * x);
    return 1.f - 2.f / (e + 1.f);
}
__device__ __forceinline__ void async_cp16(const void* gp, void* lp) {
    __builtin_amdgcn_global_load_lds(
        (const __attribute__((address_space(1))) void*)gp,
        (__attribute__((address_space(3))) void*)lp, 16, 0, 0);
}

// ---- weight packing into MFMA B-fragment order (verified R2/R3) ----
// out[((nt*KT + kt)*64 + lane)*8 + j] = B[kt*32 + (lane>>4)*8 + j][nt*16 + (lane&15)]
__global__ __launch_bounds__(256)
void pack_direct(const float* __restrict__ W, short* __restrict__ out, int K, int N)
{
    int idx = blockIdx.x * 256 + threadIdx.x;
    if (idx >= K * N) return;
    int j = idx & 7;
    int lane = (idx >> 3) & 63;
    int rest = idx >> 9;
    int KT = K >> 5;
    int kt = rest % KT;
    int nt = rest / KT;
    int k = kt * 32 + (lane >> 4) * 8 + j;
    int n = nt * 16 + (lane & 15);
    out[idx] = f2bf(W[k * N + n]);
}
__global__ __launch_bounds__(256)
void pack_trans(const float* __restrict__ W, short* __restrict__ out, int K, int N)
{
    int idx = blockIdx.x * 256 + threadIdx.x;
    if (idx >= K * N) return;
    int j = idx & 7;
    int lane = (idx >> 3) & 63;
    int rest = idx >> 9;
    int KT = K >> 5;
    int kt = rest % KT;
    int nt = rest / KT;
    int k = kt * 32 + (lane >> 4) * 8 + j;
    int n = nt * 16 + (lane & 15);
    out[idx] = f2bf(W[n * K + k]);
}

// Stage one BK=64 slab: A (64x64 bf16, XOR-swizzled 16B chunks) = 8 KB,
// B (4 n-strips x 2 k-tiles of packed fragments) = 8 KB.
__device__ __forceinline__ void stage(const short* A, int lda, int row0, int kb,
                                      const short* Bp, int KT, int n0t,
                                      char* Abuf, char* Bbuf, int tid)
{
#pragma unroll
    for (int j = 0; j < 2; ++j) {
        int lin = j * 256 + tid;
        int row = lin >> 3, s = lin & 7;
        int g = (s + row) & 7;                       // swizzle on global side
        async_cp16(A + (size_t)(row0 + row) * lda + kb * 64 + g * 8, Abuf + lin * 16);
    }
#pragma unroll
    for (int j = 0; j < 2; ++j) {
        int lin = j * 256 + tid;
        int strip = lin >> 7, within = lin & 127;
        async_cp16(Bp + ((size_t)(n0t + strip) * KT + kb * 2) * 512 + within * 8,
                   Bbuf + lin * 16);
    }
}

// Wave (mr,nc) covers 32 rows x 32 cols; 2 k-tiles per slab -> 8 MFMA.
__device__ __forceinline__ void compute(const char* Abuf, const char* Bbuf,
                                        int mr, int nc, int lane, f32x4 acc[2][2])
{
    const int lrow = lane & 15, quad = lane >> 4;
#pragma unroll
    for (int ktl = 0; ktl < 2; ++ktl) {
        short8 a[2], b[2];
#pragma unroll
        for (int ai = 0; ai < 2; ++ai) {
            int r = mr * 32 + ai * 16 + lrow;
            int g = ktl * 4 + quad;
            a[ai] = *(const short8*)(Abuf + r * 128 + (((g + r) & 7) * 16));
        }
#pragma unroll
        for (int bi = 0; bi < 2; ++bi) {
            int ntl = nc * 2 + bi;
            b[bi] = *(const short8*)(Bbuf + ((ntl * 2 + ktl) * 64 + lane) * 16);
        }
#pragma unroll
        for (int ai = 0; ai < 2; ++ai)
#pragma unroll
            for (int bi = 0; bi < 2; ++bi)
                acc[ai][bi] = __builtin_amdgcn_mfma_f32_16x16x32_bf16(a[ai], b[bi], acc[ai][bi], 0, 0, 0);
    }
}

// modes: 0 C=tanh(acc+bias); 1 C=w3*(1-tanh(acc+bias)^2);
//        2 C=acc*(1-aux^2);  3 C += coef*acc (coef folded in phase1)
__global__ __launch_bounds__(256, 4)
void gemm_mfma(const short* __restrict__ A, int lda,
               const short* __restrict__ Bp, int KT,
               const float* __restrict__ bias, const float* __restrict__ w3,
               const short* __restrict__ aux, int ldaux,
               short* __restrict__ C, int ldc,
               int mode, float coef)
{
    __shared__ __align__(16) char smem[32768];
    char* const Ab0 = smem;
    char* const Ab1 = smem + 8192;
    char* const Bb0 = smem + 16384;
    char* const Bb1 = smem + 24576;

    const int tid = threadIdx.x;
    const int lane = tid & 63, wid = tid >> 6;
    const int mr = wid >> 1, nc = wid & 1;
    const int row0 = blockIdx.y * BM;
    const int n0 = blockIdx.x * BN;
    const int n0t = n0 >> 4;

    const f32x4 zf = {0.f, 0.f, 0.f, 0.f};
    f32x4 acc[2][2] = {{zf, zf}, {zf, zf}};

    const int NKB = KT >> 1;   // 16 (K=1024) or 4 (K=256)
    stage(A, lda, row0, 0, Bp, KT, n0t, Ab0, Bb0, tid);
    for (int kb = 0; kb < NKB; ++kb) {
        __syncthreads();       // drains vmcnt(0): slab kb resident
        const int cur = kb & 1;
        if (kb + 1 < NKB)
            stage(A, lda, row0, kb + 1, Bp, KT, n0t,
                  cur ? Ab0 : Ab1, cur ? Bb0 : Bb1, tid);
        compute(cur ? Ab1 : Ab0, cur ? Bb1 : Bb0, mr, nc, lane, acc);
    }
    __syncthreads();           // Ct overlaps Ab region; wait for all A reads

    // ---- phase 1: epilogue on acc -> bf16 C-tile in LDS (stride 80) ----
    short* Ct = (short*)smem;  // 64 x 80 shorts = 10 KB
    const int lrow = lane & 15, quad = lane >> 4;
#pragma unroll
    for (int bi = 0; bi < 2; ++bi) {
        const int ntl = nc * 2 + bi;
        const int gcol = n0 + ntl * 16 + lrow;
        float bb = 0.f, w3c = 0.f;
        if (mode <= 1) bb = bias[gcol];
        if (mode == 1) w3c = w3[gcol];
#pragma unroll
        for (int ai = 0; ai < 2; ++ai) {
            const int crow = mr * 32 + ai * 16 + quad * 4;
#pragma unroll
            for (int r = 0; r < 4; ++r) {
                float v = acc[ai][bi][r];
                if (mode == 0)      v = tanh_fast(v + bb);
                else if (mode == 1) { float t = tanh_fast(v + bb); v = w3c * (1.f - t * t); }
                else if (mode == 3) v = coef * v;
                Ct[(crow + r) * 80 + ntl * 16 + lrow] = f2bf(v);
            }
        }
    }
    __syncthreads();

    // ---- phase 2: coalesced 16B copy-out with optional mask / rmw ----
#pragma unroll
    for (int j = 0; j < 2; ++j) {
        int lin = j * 256 + tid;
        int row = lin >> 3, chunk = lin & 7;
        size_t goff = (size_t)(row0 + row) * ldc + n0 + chunk * 8;
        short8 v = *(const short8*)(Ct + row * 80 + chunk * 8);
        if (mode == 2) {
            short8 h = *(const short8*)(aux + (size_t)(row0 + row) * ldaux + n0 + chunk * 8);
#pragma unroll
            for (int e = 0; e < 8; ++e) {
                float hh = bf2f(h[e]);
                v[e] = f2bf(bf2f(v[e]) * (1.f - hh * hh));
            }
        } else if (mode == 3) {
            short8 zv = *(const short8*)(C + goff);
#pragma unroll
            for (int e = 0; e < 8; ++e)
                v[e] = f2bf(bf2f(zv[e]) + bf2f(v[e]));
        }
        *(short8*)(C + goff) = v;
    }
}

__global__ __launch_bounds__(256)
void init_zp(const float* __restrict__ z, short* __restrict__ zp)
{
    size_t i = (size_t)blockIdx.x * 256 + threadIdx.x;   // quads over 16384x1024
    int qc = (int)(i & 255);
    size_t r = i >> 8;
    short4v o;
    if (qc < 128) {
        const float4* z4 = (const float4*)z;
        float4 v = z4[r * 128 + qc];
        o.x = f2bf(v.x); o.y = f2bf(v.y); o.z = f2bf(v.z); o.w = f2bf(v.w);
    } else {
        o.x = 0; o.y = 0; o.z = 0; o.w = 0;
    }
    ((short4v*)zp)[i] = o;
}

__global__ __launch_bounds__(256)
void extract_q(const short* __restrict__ zp, float* __restrict__ out)
{
    size_t i = (size_t)blockIdx.x * 256 + threadIdx.x;   // quads over 16384x512
    int qc = (int)(i & 127);
    size_t r = i >> 7;
    short4v v = ((const short4v*)zp)[r * 256 + qc];
    float4 o;
    o.x = bf2f(v.x); o.y = bf2f(v.y); o.z = bf2f(v.z); o.w = bf2f(v.w);
    ((float4*)out)[i] = o;
}

extern "C" void kernel_launch(void* const* d_in, const int* in_sizes, int n_in,
                              void* d_out, int out_size, void* d_ws, size_t ws_size,
                              hipStream_t stream)
{
    const float* z  = (const float*)d_in[0];
    const float* W1 = (const float*)d_in[1];   // 1024 x 256
    const float* b1 = (const float*)d_in[2];
    const float* W2 = (const float*)d_in[3];   // 256 x 256
    const float* b2 = (const float*)d_in[4];
    const float* W3 = (const float*)d_in[5];   // 256 x 1
    float* out = (float*)d_out;

    short* zp   = (short*)d_ws;                        // 16384x1024
    short* h1   = zp   + (size_t)16384 * 1024;         // 16384x256
    short* da2  = h1   + (size_t)16384 * 256;
    short* da1  = da2  + (size_t)16384 * 256;
    short* PB1  = da1  + (size_t)16384 * 256;          // K=1024,N=256 (KT=32)
    short* PB2  = PB1  + 262144;                       // K=256,N=256  (KT=8)
    short* PB2T = PB2  + 65536;
    short* PB1T = PB2T + 65536;                        // K=256,N=1024 (KT=8)

    pack_direct<<<1024, 256, 0, stream>>>(W1, PB1, 1024, 256);
    pack_direct<<<256,  256, 0, stream>>>(W2, PB2, 256, 256);
    pack_trans <<<256,  256, 0, stream>>>(W2, PB2T, 256, 256);
    pack_trans <<<1024, 256, 0, stream>>>(W1, PB1T, 256, 1024);
    init_zp<<<16384, 256, 0, stream>>>(z, zp);

    const dim3 blk(256);
    const dim3 g2(4, 256);   // N=256 GEMMs: 1024 blocks = 4/CU
    const dim3 g4(8, 256);   // N=512 GEMM (K4): 2048 blocks

    for (int it = 0; it < 9; ++it) {
        const int call = it % 3;
        const bool isq = (call == 1);
        const int src_nt  = isq ? 32 : 0;
        const int dst_off = isq ? 0 : 512;
        const float coef  = isq ? DT : (-0.5f * DT);

        // K1: h1 = tanh(zp @ W1 + b1)
        gemm_mfma<<<g2, blk, 0, stream>>>(zp, 1024, PB1, 32, b1, b1, h1, 256,
                                          h1, 256, 0, 0.f);
        // K2: da2 = W3 * (1 - tanh(h1 @ W2 + b2)^2)
        gemm_mfma<<<g2, blk, 0, stream>>>(h1, 256, PB2, 8, b2, W3, h1, 256,
                                          da2, 256, 1, 0.f);
        // K3: da1 = (da2 @ W2^T) * (1 - h1^2)
        gemm_mfma<<<g2, blk, 0, stream>>>(da2, 256, PB2T, 8, b1, b1, h1, 256,
                                          da1, 256, 2, 0.f);
        // K4: zp[:, dst:dst+512] += coef * (da1 @ W1T[:, src:src+512])
        gemm_mfma<<<g4, blk, 0, stream>>>(da1, 256, PB1T + (size_t)src_nt * 8 * 512, 8,
                                          b1, b1, zp, 1024,
                                          zp + dst_off, 1024, 3, coef);
    }

    extract_q<<<8192, 256, 0, stream>>>(zp, out);
}

// Round 5
// 380.978 us; speedup vs baseline: 1.7012x; 1.7012x over previous
//
#include <hip/hip_runtime.h>
#include <math.h>

#define DT 0.1f

typedef __attribute__((ext_vector_type(4)))  short short4v;
typedef __attribute__((ext_vector_type(8)))  short short8;
typedef __attribute__((ext_vector_type(16))) float f32x16;

__device__ __forceinline__ short f2bf(float x) {
    unsigned int u = __float_as_uint(x);
    unsigned int r = (u + 0x7fffu + ((u >> 16) & 1u)) >> 16;  // RNE
    return (short)r;
}
__device__ __forceinline__ float bf2f(short s) {
    return __uint_as_float(((unsigned int)(unsigned short)s) << 16);
}
__device__ __forceinline__ float tanh_fast(float x) {
    float e = __expf(x + x);                       // v_mul+v_exp
    float r = __builtin_amdgcn_rcpf(e + 1.f);      // v_rcp (no slow div)
    return __builtin_fmaf(-2.f, r, 1.f);
}
__device__ __forceinline__ short8 mfma32(short8 a, short8 b, f32x16 c) {
    return (short8){};  // never used; placeholder to appease nothing
}

// ---------------- weight packing: 32x32x16 MFMA B-fragment order -----------
// B-frag: lane holds B[k = kt*16 + (lane>>5)*8 + j][n = nt*32 + (lane&31)]
// stored at out[((nt*KT + kt)*64 + lane)*8 + j],  KT = K/16
__global__ __launch_bounds__(256)
void pack32_direct(const float* __restrict__ W, short* __restrict__ out, int K, int N)
{
    int idx = blockIdx.x * 256 + threadIdx.x;
    int j = idx & 7, lane = (idx >> 3) & 63, rest = idx >> 9;
    int KT = K >> 4;
    int kt = rest % KT, nt = rest / KT;
    int k = kt * 16 + (lane >> 5) * 8 + j;
    int n = nt * 32 + (lane & 31);
    out[idx] = f2bf(W[k * N + n]);
}
__global__ __launch_bounds__(256)
void pack32_trans(const float* __restrict__ W, short* __restrict__ out, int K, int N)
{
    int idx = blockIdx.x * 256 + threadIdx.x;
    int j = idx & 7, lane = (idx >> 3) & 63, rest = idx >> 9;
    int KT = K >> 4;
    int kt = rest % KT, nt = rest / KT;
    int k = kt * 16 + (lane >> 5) * 8 + j;
    int n = nt * 32 + (lane & 31);
    out[idx] = f2bf(W[n * K + k]);
}

// z (16384x512 fp32) -> A-fragment-packed bf16: frag idx ((rt*32+kt)*64+lane)
__global__ __launch_bounds__(256)
void pack_zA(const float* __restrict__ z, short* __restrict__ out)
{
    int idx = blockIdx.x * 256 + threadIdx.x;        // 16384*512 total
    int j = idx & 7, lane = (idx >> 3) & 63, rest = idx >> 9;
    int kt = rest & 31, rt = rest >> 5;
    int m = lane & 31;
    int k = kt * 16 + (lane >> 5) * 8 + j;
    out[idx] = f2bf(z[(size_t)(rt * 32 + m) * 512 + k]);
}

// S_qp = -0.5*dt * W1^T[:, :512] @ W1[512:, :]   (k-row = b)
// S_pq =      dt * W1^T[:, 512:] @ W1[:512, :]
__global__ __launch_bounds__(256)
void compute_S(const float* __restrict__ W1, float* __restrict__ Sq, float* __restrict__ Sp)
{
    int n = threadIdx.x;
    int b = blockIdx.x;
    float s = 0.f;
    if (b < 256) {
        int k = b;
        for (int c = 0; c < 512; ++c)
            s = __builtin_fmaf(W1[c * 256 + k], W1[(512 + c) * 256 + n], s);
        Sq[k * 256 + n] = -0.5f * DT * s;
    } else {
        int k = b - 256;
        for (int c = 0; c < 512; ++c)
            s = __builtin_fmaf(W1[(512 + c) * 256 + k], W1[c * 256 + n], s);
        Sp[k * 256 + n] = DT * s;
    }
}

// ---------------- LDS intermediate layout (C-layout-native, swizzled) -------
// Tile (nt in [0,8), mh in [0,2)): 64 lane-slots x 16 regs (bf16).
// slot = ((nt*2+mh)*64 + ls), ls = writer lane; logical reg r at physical
// short-offset ((r & ~3) + rot) & 15 ... rotation rot = ((ls>>2)&3)*4
// (same for ls and ls+32 -> readers/writers agree).
// Verified C-layout: row = (r&3) + 8*(r>>2) + 4*(lane>>5), col = lane&31.

__device__ __forceinline__ short8 lds_frag(const short* Ac, int kt, int mt2,
                                           int l31, int lh, int rot)
{
    int nt_s = kt >> 1;
    int po = (((kt & 1) * 2 + lh) * 4 + rot) & 15;
    int base = ((nt_s * 2 + mt2) * 64 + l31) * 16 + po;
    short4v x = *(const short4v*)&Ac[base];
    short4v y = *(const short4v*)&Ac[base + 512];     // +32 slots
    short8 r;
    r[0] = x.x; r[1] = x.y; r[2] = x.z; r[3] = x.w;
    r[4] = y.x; r[5] = y.y; r[6] = y.z; r[7] = y.w;
    return r;
}

__device__ __forceinline__ void store_tile(short* Ac, int nt, int mt2, int lane,
                                           int rot, const f32x16 v)
{
    int base = ((nt * 2 + mt2) * 64 + lane) * 16;
#pragma unroll
    for (int c = 0; c < 4; ++c) {
        short4v pk;
        pk.x = f2bf(v[4 * c + 0]); pk.y = f2bf(v[4 * c + 1]);
        pk.z = f2bf(v[4 * c + 2]); pk.w = f2bf(v[4 * c + 3]);
        *(short4v*)&Ac[base + ((4 * c + rot) & 15)] = pk;
    }
}

// GEMM over K=256 (16 kt): A from LDS, B fragments from global (L2-hot),
// two 32-wide output tiles. acc passed in/out (can be live state).
__device__ __forceinline__ void gemm_lds(const short* Ac, int mt2, int l31, int lh,
                                         int rot, const short8* __restrict__ Bf0,
                                         const short8* __restrict__ Bf1,
                                         f32x16& acc0, f32x16& acc1)
{
    short8 b0[4], b1[4];
#pragma unroll
    for (int k = 0; k < 4; ++k) { b0[k] = Bf0[k * 64]; b1[k] = Bf1[k * 64]; }
#pragma unroll
    for (int kt = 0; kt < 16; ++kt) {
        short8 a = lds_frag(Ac, kt, mt2, l31, lh, rot);
        short8 cb0 = b0[kt & 3], cb1 = b1[kt & 3];
        if (kt + 4 < 16) {
            b0[kt & 3] = Bf0[(kt + 4) * 64];
            b1[kt & 3] = Bf1[(kt + 4) * 64];
        }
        acc0 = __builtin_amdgcn_mfma_f32_32x32x16_bf16(a, cb0, acc0, 0, 0, 0);
        acc1 = __builtin_amdgcn_mfma_f32_32x32x16_bf16(a, cb1, acc1, 0, 0, 0);
    }
}

// ---------------- the fused leapfrog (8 gradH evals, state in registers) ----
__global__ __launch_bounds__(512, 2)
void mega(const short* __restrict__ zpA,
          const short* __restrict__ PB1q,
          const short* __restrict__ PB2,
          const short* __restrict__ PB2T,
          const short* __restrict__ PBSq,
          const short* __restrict__ PBSp,
          const float* __restrict__ b1,
          const float* __restrict__ b2,
          const float* __restrict__ W3,
          short* __restrict__ dsumP)
{
    __shared__ short h1_c[16384];   // 8 nt x 2 mh x 64 x 16
    __shared__ short da_c[16384];

    const int tid = threadIdx.x;
    const int lane = tid & 63, w = tid >> 6;
    const int mt2 = w >> 2, nq = w & 3;
    const int l31 = lane & 31, lh = lane >> 5;
    const int rot = ((l31 >> 2) & 3) * 4;
    const int bx = blockIdx.x;

    const int c0 = (2 * nq) * 32 + l31, c1 = (2 * nq + 1) * 32 + l31;
    const float b1v[2] = {b1[c0], b1[c1]};
    const float b2v[2] = {b2[c0], b2[c1]};
    const float w3v[2] = {W3[c0], W3[c1]};

    f32x16 a1[2];  a1[0] = 0.f; a1[1] = 0.f;
    f32x16 dsum[2]; dsum[0] = 0.f; dsum[1] = 0.f;

    // GEMM1: a1 = z @ W1[:512,:]   (K=512, 32 kt; A and B from global)
    {
        const int rt32 = bx * 2 + mt2;
        const short8* Af  = (const short8*)zpA  + (size_t)rt32 * 32 * 64 + lane;
        const short8* Bf0 = (const short8*)PB1q + (size_t)(2 * nq) * 32 * 64 + lane;
        const short8* Bf1 = (const short8*)PB1q + (size_t)(2 * nq + 1) * 32 * 64 + lane;
        short8 ar[4], b0[4], b1r[4];
#pragma unroll
        for (int k = 0; k < 4; ++k) {
            ar[k] = Af[k * 64]; b0[k] = Bf0[k * 64]; b1r[k] = Bf1[k * 64];
        }
#pragma unroll 8
        for (int kt = 0; kt < 32; ++kt) {
            short8 a = ar[kt & 3], cb0 = b0[kt & 3], cb1 = b1r[kt & 3];
            if (kt + 4 < 32) {
                ar[kt & 3]  = Af[(kt + 4) * 64];
                b0[kt & 3]  = Bf0[(kt + 4) * 64];
                b1r[kt & 3] = Bf1[(kt + 4) * 64];
            }
            a1[0] = __builtin_amdgcn_mfma_f32_32x32x16_bf16(a, cb0, a1[0], 0, 0, 0);
            a1[1] = __builtin_amdgcn_mfma_f32_32x32x16_bf16(a, cb1, a1[1], 0, 0, 0);
        }
    }

    const short8* PB2f  = (const short8*)PB2;
    const short8* PB2Tf = (const short8*)PB2T;
    const short8* PBSqf = (const short8*)PBSq;
    const short8* PBSpf = (const short8*)PBSp;

    for (int it = 0; it < 8; ++it) {
        const bool isq = ((it % 3) == 1);

        // P1: h1 = tanh(a1 + b1) -> h1_c
#pragma unroll
        for (int t = 0; t < 2; ++t) {
            f32x16 hv;
#pragma unroll
            for (int r = 0; r < 16; ++r) hv[r] = tanh_fast(a1[t][r] + b1v[t]);
            store_tile(h1_c, 2 * nq + t, mt2, lane, rot, hv);
        }
        __syncthreads();

        // P2: t2 = h1 @ W2;  da2 = W3*(1-tanh^2(t2+b2)) -> da_c
        {
            f32x16 t2a = 0.f, t2b = 0.f;
            gemm_lds(h1_c, mt2, l31, lh, rot,
                     PB2f + (2 * nq) * 1024 + lane, PB2f + (2 * nq + 1) * 1024 + lane,
                     t2a, t2b);
            f32x16 d2[2];
#pragma unroll
            for (int r = 0; r < 16; ++r) {
                float ta = tanh_fast(t2a[r] + b2v[0]);
                float tb = tanh_fast(t2b[r] + b2v[1]);
                d2[0][r] = w3v[0] * (1.f - ta * ta);
                d2[1][r] = w3v[1] * (1.f - tb * tb);
            }
            store_tile(da_c, 2 * nq, mt2, lane, rot, d2[0]);
            store_tile(da_c, 2 * nq + 1, mt2, lane, rot, d2[1]);
        }
        __syncthreads();

        // P3: t3 = da2 @ W2^T;  da1 = t3*(1-h1^2)
        {
            f32x16 t3a = 0.f, t3b = 0.f;
            gemm_lds(da_c, mt2, l31, lh, rot,
                     PB2Tf + (2 * nq) * 1024 + lane, PB2Tf + (2 * nq + 1) * 1024 + lane,
                     t3a, t3b);
            // read back own h1 values (register-native slots)
            float hva[16], hvb[16];
#pragma unroll
            for (int c = 0; c < 4; ++c) {
                int ba = ((2 * nq) * 2 + mt2) * 64 + lane;
                int bb = ((2 * nq + 1) * 2 + mt2) * 64 + lane;
                short4v ha = *(const short4v*)&h1_c[ba * 16 + ((4 * c + rot) & 15)];
                short4v hb = *(const short4v*)&h1_c[bb * 16 + ((4 * c + rot) & 15)];
                hva[4 * c + 0] = bf2f(ha.x); hva[4 * c + 1] = bf2f(ha.y);
                hva[4 * c + 2] = bf2f(ha.z); hva[4 * c + 3] = bf2f(ha.w);
                hvb[4 * c + 0] = bf2f(hb.x); hvb[4 * c + 1] = bf2f(hb.y);
                hvb[4 * c + 2] = bf2f(hb.z); hvb[4 * c + 3] = bf2f(hb.w);
            }
            __syncthreads();   // all waves done reading da2 before overwrite
            f32x16 d1[2];
#pragma unroll
            for (int r = 0; r < 16; ++r) {
                d1[0][r] = t3a[r] * (1.f - hva[r] * hva[r]);
                d1[1][r] = t3b[r] * (1.f - hvb[r] * hvb[r]);
            }
            if (isq) { dsum[0] += d1[0]; dsum[1] += d1[1]; }
            if (it < 7) {
                store_tile(da_c, 2 * nq, mt2, lane, rot, d1[0]);
                store_tile(da_c, 2 * nq + 1, mt2, lane, rot, d1[1]);
            }
        }
        __syncthreads();

        // P4: a1 += da1 @ S  (coef folded into S; skipped on last eval)
        if (it < 7) {
            const short8* Sf = isq ? PBSpf : PBSqf;
            gemm_lds(da_c, mt2, l31, lh, rot,
                     Sf + (2 * nq) * 1024 + lane, Sf + (2 * nq + 1) * 1024 + lane,
                     a1[0], a1[1]);
        }
    }

    // write dsum -> da_c, then emit A-fragment-packed dsumP
    store_tile(da_c, 2 * nq, mt2, lane, rot, dsum[0]);
    store_tile(da_c, 2 * nq + 1, mt2, lane, rot, dsum[1]);
    __syncthreads();
#pragma unroll
    for (int kk = 0; kk < 4; ++kk) {
        int kt = nq * 4 + kk;
        short8 f = lds_frag(da_c, kt, mt2, l31, lh, rot);
        *(short8*)(dsumP + ((size_t)((bx * 2 + mt2) * 16 + kt) * 64 + lane) * 8) = f;
    }
}

// ---------------- final: out = z + dt * (dsum @ W1^T[:,512:]) ---------------
__global__ __launch_bounds__(512, 2)
void out_gemm(const short* __restrict__ dsumP, const short* __restrict__ PB1Tp,
              const float* __restrict__ z, float* __restrict__ out)
{
    const int tid = threadIdx.x;
    const int lane = tid & 63, w = tid >> 6;
    const int mt2 = w >> 2, nq = w & 3;
    const int l31 = lane & 31, lh = lane >> 5;
    const int bx = blockIdx.x;
    const int rt32 = bx * 2 + mt2;

    f32x16 acc[4];
#pragma unroll
    for (int t = 0; t < 4; ++t) acc[t] = 0.f;

    const short8* Af = (const short8*)dsumP + (size_t)rt32 * 16 * 64 + lane;
    const short8* Bf[4];
#pragma unroll
    for (int t = 0; t < 4; ++t)
        Bf[t] = (const short8*)PB1Tp + (size_t)(nq * 4 + t) * 16 * 64 + lane;

    short8 ar[2], br[2][4];
#pragma unroll
    for (int k = 0; k < 2; ++k) {
        ar[k] = Af[k * 64];
#pragma unroll
        for (int t = 0; t < 4; ++t) br[k][t] = Bf[t][k * 64];
    }
#pragma unroll
    for (int kt = 0; kt < 16; ++kt) {
        short8 a = ar[kt & 1];
        short8 bb[4];
#pragma unroll
        for (int t = 0; t < 4; ++t) bb[t] = br[kt & 1][t];
        if (kt + 2 < 16) {
            ar[kt & 1] = Af[(kt + 2) * 64];
#pragma unroll
            for (int t = 0; t < 4; ++t) br[kt & 1][t] = Bf[t][(kt + 2) * 64];
        }
#pragma unroll
        for (int t = 0; t < 4; ++t)
            acc[t] = __builtin_amdgcn_mfma_f32_32x32x16_bf16(a, bb[t], acc[t], 0, 0, 0);
    }

#pragma unroll
    for (int t = 0; t < 4; ++t) {
        const int col = (nq * 4 + t) * 32 + l31;
#pragma unroll
        for (int r = 0; r < 16; ++r) {
            int row = bx * 64 + mt2 * 32 + (r & 3) + 8 * (r >> 2) + 4 * lh;
            size_t i = (size_t)row * 512 + col;
            out[i] = z[i] + DT * acc[t][r];
        }
    }
}

extern "C" void kernel_launch(void* const* d_in, const int* in_sizes, int n_in,
                              void* d_out, int out_size, void* d_ws, size_t ws_size,
                              hipStream_t stream)
{
    const float* z  = (const float*)d_in[0];
    const float* W1 = (const float*)d_in[1];   // 1024 x 256
    const float* b1 = (const float*)d_in[2];
    const float* W2 = (const float*)d_in[3];   // 256 x 256
    const float* b2 = (const float*)d_in[4];
    const float* W3 = (const float*)d_in[5];   // 256 x 1
    float* out = (float*)d_out;

    float* Sq_f  = (float*)d_ws;               // 256x256
    float* Sp_f  = Sq_f + 65536;
    short* PB2   = (short*)(Sp_f + 65536);     // 65536
    short* PB2T  = PB2   + 65536;
    short* PBSq  = PB2T  + 65536;
    short* PBSp  = PBSq  + 65536;
    short* PB1q  = PBSp  + 65536;              // 131072 (K=512,N=256)
    short* PB1Tp = PB1q  + 131072;             // 131072 (K=256,N=512)
    short* zpA   = PB1Tp + 131072;             // 8388608 (16 MB)
    short* dsumP = zpA   + 8388608;            // 4194304 (8 MB)

    compute_S<<<512, 256, 0, stream>>>(W1, Sq_f, Sp_f);
    pack32_direct<<<256, 256, 0, stream>>>(W2, PB2, 256, 256);
    pack32_trans <<<256, 256, 0, stream>>>(W2, PB2T, 256, 256);
    pack32_direct<<<256, 256, 0, stream>>>(Sq_f, PBSq, 256, 256);
    pack32_direct<<<256, 256, 0, stream>>>(Sp_f, PBSp, 256, 256);
    pack32_direct<<<512, 256, 0, stream>>>(W1, PB1q, 512, 256);
    pack32_trans <<<512, 256, 0, stream>>>(W1 + 512 * 256, PB1Tp, 256, 512);
    pack_zA<<<32768, 256, 0, stream>>>(z, zpA);

    mega<<<256, 512, 0, stream>>>(zpA, PB1q, PB2, PB2T, PBSq, PBSp,
                                  b1, b2, W3, dsumP);
    out_gemm<<<256, 512, 0, stream>>>(dsumP, PB1Tp, z, out);
}

// Round 6
// 216.761 us; speedup vs baseline: 2.9900x; 1.7576x over previous
//
#include <hip/hip_runtime.h>
#include <math.h>

#define DT 0.1f

typedef __attribute__((ext_vector_type(4)))  short short4v;
typedef __attribute__((ext_vector_type(8)))  short short8;
typedef __attribute__((ext_vector_type(16))) float f32x16;

__device__ __forceinline__ short f2bf(float x) {
    unsigned int u = __float_as_uint(x);
    unsigned int r = (u + 0x7fffu + ((u >> 16) & 1u)) >> 16;  // RNE
    return (short)r;
}
__device__ __forceinline__ float bf2f(short s) {
    return __uint_as_float(((unsigned int)(unsigned short)s) << 16);
}
__device__ __forceinline__ float tanh_fast(float x) {
    float e = __expf(x + x);
    float r = __builtin_amdgcn_rcpf(e + 1.f);
    return __builtin_fmaf(-2.f, r, 1.f);
}

// ---------------- weight packing: 32x32x16 MFMA B-fragment order -----------
// lane holds B[k = kt*16 + (lane>>5)*8 + j][n = nt*32 + (lane&31)]
// at out[((nt*KT + kt)*64 + lane)*8 + j],  KT = K/16   (verified R5)
__global__ __launch_bounds__(256)
void pack32_direct(const float* __restrict__ W, short* __restrict__ out, int K, int N)
{
    int idx = blockIdx.x * 256 + threadIdx.x;
    int j = idx & 7, lane = (idx >> 3) & 63, rest = idx >> 9;
    int KT = K >> 4;
    int kt = rest % KT, nt = rest / KT;
    int k = kt * 16 + (lane >> 5) * 8 + j;
    int n = nt * 32 + (lane & 31);
    out[idx] = f2bf(W[k * N + n]);
}
__global__ __launch_bounds__(256)
void pack32_trans(const float* __restrict__ W, short* __restrict__ out, int K, int N)
{
    int idx = blockIdx.x * 256 + threadIdx.x;
    int j = idx & 7, lane = (idx >> 3) & 63, rest = idx >> 9;
    int KT = K >> 4;
    int kt = rest % KT, nt = rest / KT;
    int k = kt * 16 + (lane >> 5) * 8 + j;
    int n = nt * 32 + (lane & 31);
    out[idx] = f2bf(W[n * K + k]);
}

// z (16384x512 fp32) -> A-frag-packed bf16, coalesced via LDS staging.
// frag idx ((rt*32 + kt)*64 + lane), rt = 32-row group.
__global__ __launch_bounds__(256)
void pack_zA(const float* __restrict__ z, short* __restrict__ out)
{
    __shared__ short zb[32 * 520];
    const int tid = threadIdx.x;
    const int bx = blockIdx.x;               // 512 blocks x 32 rows
#pragma unroll
    for (int j = 0; j < 16; ++j) {
        int lin = j * 256 + tid;             // 4096 float4
        int r = lin >> 7, c4 = lin & 127;
        float4 v = ((const float4*)z)[(size_t)(bx * 32 + r) * 128 + c4];
        short4v pk;
        pk.x = f2bf(v.x); pk.y = f2bf(v.y); pk.z = f2bf(v.z); pk.w = f2bf(v.w);
        *(short4v*)&zb[r * 520 + c4 * 4] = pk;
    }
    __syncthreads();
    const int lane = tid & 63, w = tid >> 6;
    const int m = lane & 31, lh = lane >> 5;
#pragma unroll
    for (int j = 0; j < 8; ++j) {
        int kt = w * 8 + j;
        short8 f = *(const short8*)&zb[m * 520 + kt * 16 + lh * 8];
        *(short8*)(out + (((size_t)bx * 32 + kt) * 64 + lane) * 8) = f;
    }
}

// S_qp = -0.5*dt * W1^T[:, :512] @ W1[512:, :]
// S_pq =      dt * W1^T[:, 512:] @ W1[:512, :]
__global__ __launch_bounds__(256)
void compute_S(const float* __restrict__ W1, float* __restrict__ Sq, float* __restrict__ Sp)
{
    int n = threadIdx.x;
    int b = blockIdx.x;
    float s = 0.f;
    if (b < 256) {
        int k = b;
        for (int c = 0; c < 512; ++c)
            s = __builtin_fmaf(W1[c * 256 + k], W1[(512 + c) * 256 + n], s);
        Sq[k * 256 + n] = -0.5f * DT * s;
    } else {
        int k = b - 256;
        for (int c = 0; c < 512; ++c)
            s = __builtin_fmaf(W1[(512 + c) * 256 + k], W1[c * 256 + n], s);
        Sp[k * 256 + n] = DT * s;
    }
}

// ---------------- LDS tile layout (C-layout-native, rotation swizzle) ------
// (verified R5) tile (nt,mt2): 64 slots x 16 shorts; rot = ((l31>>2)&3)*4
__device__ __forceinline__ short8 lds_frag(const short* Ac, int kt, int mt2,
                                           int l31, int lh, int rot)
{
    int nt_s = kt >> 1;
    int po = (((kt & 1) * 2 + lh) * 4 + rot) & 15;
    int base = ((nt_s * 2 + mt2) * 64 + l31) * 16 + po;
    short4v x = *(const short4v*)&Ac[base];
    short4v y = *(const short4v*)&Ac[base + 512];
    short8 r;
    r[0] = x.x; r[1] = x.y; r[2] = x.z; r[3] = x.w;
    r[4] = y.x; r[5] = y.y; r[6] = y.z; r[7] = y.w;
    return r;
}
__device__ __forceinline__ void store_tile(short* Ac, int nt, int mt2, int lane,
                                           int rot, const f32x16 v)
{
    int base = ((nt * 2 + mt2) * 64 + lane) * 16;
#pragma unroll
    for (int c = 0; c < 4; ++c) {
        short4v pk;
        pk.x = f2bf(v[4 * c + 0]); pk.y = f2bf(v[4 * c + 1]);
        pk.z = f2bf(v[4 * c + 2]); pk.w = f2bf(v[4 * c + 3]);
        *(short4v*)&Ac[base + ((4 * c + rot) & 15)] = pk;
    }
}

// K=256 gemm: A (both mt tiles) from LDS, B (this wave's nt strip) from L2.
__device__ __forceinline__ void gemm_nt(const short* Ac, int l31, int lh, int rot,
                                        const short8* __restrict__ Bf,
                                        f32x16& acc0, f32x16& acc1)
{
    short8 pb[4];
#pragma unroll
    for (int k = 0; k < 4; ++k) pb[k] = Bf[k * 64];
    short8 pa0 = lds_frag(Ac, 0, 0, l31, lh, rot);
    short8 pa1 = lds_frag(Ac, 0, 1, l31, lh, rot);
#pragma unroll
    for (int kt = 0; kt < 16; ++kt) {
        short8 ca0 = pa0, ca1 = pa1, cb = pb[kt & 3];
        if (kt + 4 < 16) pb[kt & 3] = Bf[(kt + 4) * 64];
        if (kt + 1 < 16) {
            pa0 = lds_frag(Ac, kt + 1, 0, l31, lh, rot);
            pa1 = lds_frag(Ac, kt + 1, 1, l31, lh, rot);
        }
        acc0 = __builtin_amdgcn_mfma_f32_32x32x16_bf16(ca0, cb, acc0, 0, 0, 0);
        acc1 = __builtin_amdgcn_mfma_f32_32x32x16_bf16(ca1, cb, acc1, 0, 0, 0);
    }
}

// ---------------- fused leapfrog: 1 block/CU, wave = 64 rows x 32 cols -----
__global__ __launch_bounds__(512, 2)
void mega(const short* __restrict__ zpA,
          const short* __restrict__ PB1q,
          const short* __restrict__ PB2,
          const short* __restrict__ PB2T,
          const short* __restrict__ PBSq,
          const short* __restrict__ PBSp,
          const float* __restrict__ b1,
          const float* __restrict__ b2,
          const float* __restrict__ W3,
          short* __restrict__ dsumP)
{
    __shared__ short h1_c[16384];   // 8 nt x 2 mt x 64 x 16
    __shared__ short da_c[16384];

    const int tid = threadIdx.x;
    const int lane = tid & 63, w = tid >> 6;   // w = nt strip, 0..7
    const int l31 = lane & 31, lh = lane >> 5;
    const int rot = ((l31 >> 2) & 3) * 4;
    const int bx = blockIdx.x;

    const int col = w * 32 + l31;
    const float b1v = b1[col], b2v = b2[col], w3v = W3[col];

    f32x16 A1[2];  A1[0] = 0.f; A1[1] = 0.f;
    f32x16 dsum[2]; dsum[0] = 0.f; dsum[1] = 0.f;

    // GEMM1: A1 = z @ W1[:512,:]  (K=512, A frags from global, KT=32)
    {
        const short8* Af0 = (const short8*)zpA + ((size_t)(bx * 2 + 0) * 32) * 64 + lane;
        const short8* Af1 = (const short8*)zpA + ((size_t)(bx * 2 + 1) * 32) * 64 + lane;
        const short8* Bf  = (const short8*)PB1q + ((size_t)w * 32) * 64 + lane;
        short8 pa0[2], pa1[2], pb[4];
#pragma unroll
        for (int k = 0; k < 2; ++k) { pa0[k] = Af0[k * 64]; pa1[k] = Af1[k * 64]; }
#pragma unroll
        for (int k = 0; k < 4; ++k) pb[k] = Bf[k * 64];
#pragma unroll
        for (int kt = 0; kt < 32; ++kt) {
            short8 ca0 = pa0[kt & 1], ca1 = pa1[kt & 1], cb = pb[kt & 3];
            if (kt + 2 < 32) {
                pa0[kt & 1] = Af0[(kt + 2) * 64];
                pa1[kt & 1] = Af1[(kt + 2) * 64];
            }
            if (kt + 4 < 32) pb[kt & 3] = Bf[(kt + 4) * 64];
            A1[0] = __builtin_amdgcn_mfma_f32_32x32x16_bf16(ca0, cb, A1[0], 0, 0, 0);
            A1[1] = __builtin_amdgcn_mfma_f32_32x32x16_bf16(ca1, cb, A1[1], 0, 0, 0);
        }
    }

    for (int it = 0; it < 8; ++it) {
        const bool isq = ((it % 3) == 1);

        // P1: h1 = tanh(A1 + b1)
#pragma unroll
        for (int t = 0; t < 2; ++t) {
            f32x16 hv;
#pragma unroll
            for (int r = 0; r < 16; ++r) hv[r] = tanh_fast(A1[t][r] + b1v);
            store_tile(h1_c, w, t, lane, rot, hv);
        }
        __syncthreads();

        // P2: da2 = W3*(1-tanh^2(h1@W2 + b2))
        {
            f32x16 t0 = 0.f, t1 = 0.f;
            gemm_nt(h1_c, l31, lh, rot, (const short8*)PB2 + ((size_t)w * 16) * 64 + lane, t0, t1);
#pragma unroll
            for (int t = 0; t < 2; ++t) {
                f32x16& tt = t ? t1 : t0;
                f32x16 d;
#pragma unroll
                for (int r = 0; r < 16; ++r) {
                    float ta = tanh_fast(tt[r] + b2v);
                    d[r] = w3v * (1.f - ta * ta);
                }
                store_tile(da_c, w, t, lane, rot, d);
            }
        }
        __syncthreads();

        // P3: da1 = (da2@W2^T) * (1-h1^2)
        {
            f32x16 t0 = 0.f, t1 = 0.f;
            gemm_nt(da_c, l31, lh, rot, (const short8*)PB2T + ((size_t)w * 16) * 64 + lane, t0, t1);
            __syncthreads();   // all waves done reading da2
#pragma unroll
            for (int t = 0; t < 2; ++t) {
                f32x16& tt = t ? t1 : t0;
                f32x16 d;
                const int basei = ((w * 2 + t) * 64 + lane) * 16;
#pragma unroll
                for (int c = 0; c < 4; ++c) {
                    short4v h4 = *(const short4v*)&h1_c[basei + ((4 * c + rot) & 15)];
                    float h0 = bf2f(h4.x), h1f = bf2f(h4.y);
                    float h2 = bf2f(h4.z), h3 = bf2f(h4.w);
                    d[4 * c + 0] = tt[4 * c + 0] * (1.f - h0 * h0);
                    d[4 * c + 1] = tt[4 * c + 1] * (1.f - h1f * h1f);
                    d[4 * c + 2] = tt[4 * c + 2] * (1.f - h2 * h2);
                    d[4 * c + 3] = tt[4 * c + 3] * (1.f - h3 * h3);
                }
                if (isq) dsum[t] += d;
                store_tile(da_c, w, t, lane, rot, d);
            }
        }
        __syncthreads();

        // P4: A1 += da1 @ S  (coef folded into S; skip on last eval)
        if (it < 7) {
            const short* S = isq ? PBSp : PBSq;
            gemm_nt(da_c, l31, lh, rot, (const short8*)S + ((size_t)w * 16) * 64 + lane,
                    A1[0], A1[1]);
            // safe: every wave's P4 reads complete before it reaches the
            // next-iteration P1 barrier, which precedes any da_c overwrite.
        }
    }

    // pack dsum -> A-frag layout for out_gemm
    store_tile(da_c, w, 0, lane, rot, dsum[0]);
    store_tile(da_c, w, 1, lane, rot, dsum[1]);
    __syncthreads();
    const int mt2 = w >> 2;
#pragma unroll
    for (int kk = 0; kk < 4; ++kk) {
        int kt = (w & 3) * 4 + kk;
        short8 f = lds_frag(da_c, kt, mt2, l31, lh, rot);
        *(short8*)(dsumP + (((size_t)(bx * 2 + mt2) * 16 + kt) * 64 + lane) * 8) = f;
    }
}

// ---------------- final: out = z + dt * (dsum @ W1^T[:,512:]) --------------
__global__ __launch_bounds__(512, 2)
void out_gemm(const short* __restrict__ dsumP, const short* __restrict__ PB1Tp,
              const float* __restrict__ z, float* __restrict__ out)
{
    __shared__ float Ct[32 * 512];   // 64 KB

    const int tid = threadIdx.x;
    const int lane = tid & 63, w = tid >> 6;
    const int mt2 = w >> 2, nq = w & 3;
    const int l31 = lane & 31, lh = lane >> 5;
    const int bx = blockIdx.x;
    const int rt32 = bx * 2 + mt2;

    f32x16 acc[4];
#pragma unroll
    for (int t = 0; t < 4; ++t) acc[t] = 0.f;

    const short8* Af = (const short8*)dsumP + (size_t)rt32 * 16 * 64 + lane;
    const short8* Bf[4];
#pragma unroll
    for (int t = 0; t < 4; ++t)
        Bf[t] = (const short8*)PB1Tp + (size_t)(nq * 4 + t) * 16 * 64 + lane;

    short8 ar[2], br[2][4];
#pragma unroll
    for (int k = 0; k < 2; ++k) {
        ar[k] = Af[k * 64];
#pragma unroll
        for (int t = 0; t < 4; ++t) br[k][t] = Bf[t][k * 64];
    }
#pragma unroll
    for (int kt = 0; kt < 16; ++kt) {
        short8 a = ar[kt & 1];
        short8 bb[4];
#pragma unroll
        for (int t = 0; t < 4; ++t) bb[t] = br[kt & 1][t];
        if (kt + 2 < 16) {
            ar[kt & 1] = Af[(kt + 2) * 64];
#pragma unroll
            for (int t = 0; t < 4; ++t) br[kt & 1][t] = Bf[t][(kt + 2) * 64];
        }
#pragma unroll
        for (int t = 0; t < 4; ++t)
            acc[t] = __builtin_amdgcn_mfma_f32_32x32x16_bf16(a, bb[t], acc[t], 0, 0, 0);
    }

    // coalesced epilogue via LDS fp32, two 32-row passes
#pragma unroll
    for (int p = 0; p < 2; ++p) {
        if (mt2 == p) {
#pragma unroll
            for (int t = 0; t < 4; ++t) {
                const int c = (nq * 4 + t) * 32 + l31;
#pragma unroll
                for (int r = 0; r < 16; ++r) {
                    int row = (r & 3) + 8 * (r >> 2) + 4 * lh;
                    Ct[row * 512 + c] = acc[t][r];
                }
            }
        }
        __syncthreads();
#pragma unroll
        for (int j = 0; j < 8; ++j) {
            int lin = j * 512 + tid;          // 4096 float4
            int r = lin >> 7, c4 = lin & 127;
            size_t gi = (size_t)(bx * 64 + p * 32 + r) * 128 + c4;
            float4 zv = ((const float4*)z)[gi];
            float4 cv = *(const float4*)&Ct[r * 512 + c4 * 4];
            float4 ov;
            ov.x = zv.x + DT * cv.x; ov.y = zv.y + DT * cv.y;
            ov.z = zv.z + DT * cv.z; ov.w = zv.w + DT * cv.w;
            ((float4*)out)[gi] = ov;
        }
        __syncthreads();
    }
}

extern "C" void kernel_launch(void* const* d_in, const int* in_sizes, int n_in,
                              void* d_out, int out_size, void* d_ws, size_t ws_size,
                              hipStream_t stream)
{
    const float* z  = (const float*)d_in[0];
    const float* W1 = (const float*)d_in[1];   // 1024 x 256
    const float* b1 = (const float*)d_in[2];
    const float* W2 = (const float*)d_in[3];   // 256 x 256
    const float* b2 = (const float*)d_in[4];
    const float* W3 = (const float*)d_in[5];   // 256 x 1
    float* out = (float*)d_out;

    float* Sq_f  = (float*)d_ws;               // 256x256
    float* Sp_f  = Sq_f + 65536;
    short* PB2   = (short*)(Sp_f + 65536);
    short* PB2T  = PB2   + 65536;
    short* PBSq  = PB2T  + 65536;
    short* PBSp  = PBSq  + 65536;
    short* PB1q  = PBSp  + 65536;              // K=512,N=256
    short* PB1Tp = PB1q  + 131072;             // K=256,N=512
    short* zpA   = PB1Tp + 131072;             // 16 MB
    short* dsumP = zpA   + 8388608;            // 8 MB

    compute_S<<<512, 256, 0, stream>>>(W1, Sq_f, Sp_f);
    pack32_direct<<<256, 256, 0, stream>>>(W2, PB2, 256, 256);
    pack32_trans <<<256, 256, 0, stream>>>(W2, PB2T, 256, 256);
    pack32_direct<<<256, 256, 0, stream>>>(Sq_f, PBSq, 256, 256);
    pack32_direct<<<256, 256, 0, stream>>>(Sp_f, PBSp, 256, 256);
    pack32_direct<<<512, 256, 0, stream>>>(W1, PB1q, 512, 256);
    pack32_trans <<<512, 256, 0, stream>>>(W1 + 512 * 256, PB1Tp, 256, 512);
    pack_zA<<<512, 256, 0, stream>>>(z, zpA);

    mega<<<256, 512, 0, stream>>>(zpA, PB1q, PB2, PB2T, PBSq, PBSp,
                                  b1, b2, W3, dsumP);
    out_gemm<<<256, 512, 0, stream>>>(dsumP, PB1Tp, z, out);
}